// Round 2
// baseline (980.855 us; speedup 1.0000x reference)
//
#include <hip/hip_runtime.h>
#include <hip/hip_bf16.h>
#include <stdint.h>

typedef __bf16 bf16_t;
typedef __bf16 bf16x8 __attribute__((ext_vector_type(8)));
typedef float f32x4 __attribute__((ext_vector_type(4)));

// ---------- constants ----------
#define BS       4096
#define CB       1024        // batch chunk
#define NCHUNK   4
#define SEQ      20
#define SEQP     22          // padded rows per batch elem (2 zero rows)
#define EMB      768
#define FEAT     512
#define MC       (CB*SEQ)    // 20480 rows per chunk
#define KA       2304        // 3*768 virtual K
// d_out layout (floats)
#define WV_BASE   (41943040L)   // 4096*512*20
#define SENT_BASE (44040192L)

// ws layout (bytes) — total ~112 MB
#define BT_OFF    0L                        // 1536*2304*2 = 7077888
#define WPT_OFF   7077888L                  // 512*768*2   = 786432
#define SENTX_OFF 7864320L                  // 4096*768*2  = 6291456
#define XPAD_OFF  14155776L                 // 1024*22*768*2 = 34603008
#define P_OFF     48758784L                 // 3*20480*512*2 = 62914560
#define WS_NEED   111673344L

__device__ __forceinline__ void async_copy16(void* lds, const void* g) {
  __builtin_amdgcn_global_load_lds(
      (__attribute__((address_space(1))) void*)(void*)g,
      (__attribute__((address_space(3))) void*)lds,
      16, 0, 0);
}

// ---------- pack kernels ----------
// one chunk of words [CB,20,768] fp32 -> Xpad [CB,22,768] bf16 (rows 20,21 zero)
__global__ void pack_xpad(const float* __restrict__ words, bf16_t* __restrict__ Xpad) {
  long idx4 = ((long)blockIdx.x * blockDim.x + threadIdx.x) * 4;   // < CB*22*768
  long row = idx4 / EMB;          // b_local*22 + r
  int  d   = (int)(idx4 % EMB);
  long b   = row / SEQP;
  int  r   = (int)(row % SEQP);
  ushort4 o;
  if (r < SEQ) {
    float4 v = *(const float4*)(words + ((b * SEQ + r) * EMB + d));
    o.x = __builtin_bit_cast(unsigned short, (bf16_t)v.x);
    o.y = __builtin_bit_cast(unsigned short, (bf16_t)v.y);
    o.z = __builtin_bit_cast(unsigned short, (bf16_t)v.z);
    o.w = __builtin_bit_cast(unsigned short, (bf16_t)v.w);
  } else {
    o.x = 0; o.y = 0; o.z = 0; o.w = 0;
  }
  *(ushort4*)(&Xpad[idx4]) = o;
}

__global__ void pack_sent(const float* __restrict__ sent, bf16_t* __restrict__ Xs) {
  long idx4 = ((long)blockIdx.x * blockDim.x + threadIdx.x) * 4;   // < 4096*768
  float4 v = *(const float4*)(sent + idx4);
  ushort4 o;
  o.x = __builtin_bit_cast(unsigned short, (bf16_t)v.x);
  o.y = __builtin_bit_cast(unsigned short, (bf16_t)v.y);
  o.z = __builtin_bit_cast(unsigned short, (bf16_t)v.z);
  o.w = __builtin_bit_cast(unsigned short, (bf16_t)v.w);
  *(ushort4*)(&Xs[idx4]) = o;
}

// Bt[n][k], n in [0,1536), k in [0,2304): group g=n>>9, c=n&511, j=k/768, d=k%768
__global__ void pack_bt(const float* __restrict__ W1, const float* __restrict__ W2,
                        const float* __restrict__ W3, bf16_t* __restrict__ Bt) {
  long idx = (long)blockIdx.x * blockDim.x + threadIdx.x;          // < 1536*2304
  int n = (int)(idx / KA), k = (int)(idx % KA);
  int g = n >> 9, c = n & 511;
  int j = k / EMB, d = k % EMB;
  float v = 0.f;
  if (j <= g) {
    const float* W = (g == 0) ? W1 : ((g == 1) ? W2 : W3);
    v = W[((long)j * EMB + d) * FEAT + c];
  }
  Bt[idx] = (bf16_t)v;
}

// Wpt[n][k] = Wp[k][n]
__global__ void pack_wpt(const float* __restrict__ Wp, bf16_t* __restrict__ Wpt) {
  long idx = (long)blockIdx.x * blockDim.x + threadIdx.x;          // < 512*768
  int n = (int)(idx / EMB), k = (int)(idx % EMB);
  Wpt[idx] = (bf16_t)Wp[(long)k * FEAT + n];
}

// ---------- GEMM ----------
// MODE 0: conv GEMM on one chunk. A = Xpad [CB,22,768] (virtual rows:
//         rowstart=(m/20)*22+m%20, K contiguous up to 2304). Bt=[1536][2304].
//         Keff = 768*(g+1), g = blockIdx.y>>2. Epilogue: +bias_g, ReLU,
//         zero rows with l >= 20-g, store bf16 to P[g][m][c].
// MODE 1: sent GEMM. A = sentX [4096][768], Bt = Wpt [512][768], +bp, fp32 to S.
template <int MODE>
__global__ __launch_bounds__(256, 2)
void gemm_k(const bf16_t* __restrict__ A, const bf16_t* __restrict__ Bt,
            const float* __restrict__ bias1, const float* __restrict__ bias2,
            const float* __restrict__ bias3,
            bf16_t* __restrict__ P, float* __restrict__ S) {
  constexpr int LDB = (MODE == 0) ? KA : EMB;
  __shared__ bf16_t As[128 * 64];
  __shared__ bf16_t Bs[128 * 64];

  const int tid  = threadIdx.x;
  const int lane = tid & 63;
  const int w    = tid >> 6;
  const int m0   = blockIdx.x * 128;
  const int n0t  = blockIdx.y * 128;

  int g, Keff;
  if (MODE == 0) { g = blockIdx.y >> 2; Keff = EMB * (g + 1); }
  else           { g = 0;               Keff = EMB; }

  // staging: wave w stages rows [w*32, w*32+32), 4 iters of 8 rows, XOR-swizzled
  long agbase[4], bgbase[4];
  int  ldsoff[4];
  #pragma unroll
  for (int i = 0; i < 4; i++) {
    int r = w * 32 + i * 8 + (lane >> 3);
    int cg = (lane & 7) ^ (r & 7);        // global 8-elem chunk index
    int m = m0 + r;
    long rowstart = (MODE == 0) ? ((long)(m / SEQ) * SEQP + (m % SEQ)) : (long)m;
    agbase[i] = rowstart * EMB + cg * 8;
    int n = n0t + r;
    bgbase[i] = (long)n * LDB + cg * 8;
    ldsoff[i] = (w * 32 + i * 8) * 64;    // elements; HW adds lane*16B
  }

  // fragment read offsets (elements), swizzle-corrected
  const int wm = w >> 1, wn = w & 1;
  const int q = lane >> 4, ln = lane & 15;
  int aoff[4][2], boff[4][2];
  #pragma unroll
  for (int t = 0; t < 4; t++) {
    int ra = wm * 64 + t * 16 + ln;
    int rb = wn * 64 + t * 16 + ln;
    #pragma unroll
    for (int ks = 0; ks < 2; ks++) {
      int c = ks * 4 + q;
      aoff[t][ks] = ra * 64 + ((c ^ (ra & 7)) * 8);
      boff[t][ks] = rb * 64 + ((c ^ (rb & 7)) * 8);
    }
  }

  f32x4 acc[4][4];
  #pragma unroll
  for (int i = 0; i < 4; i++)
    #pragma unroll
    for (int j = 0; j < 4; j++) acc[i][j] = (f32x4)0.f;

  for (int kb = 0; kb < Keff; kb += 64) {
    #pragma unroll
    for (int i = 0; i < 4; i++) {
      async_copy16(&As[ldsoff[i]], A  + agbase[i] + kb);
      async_copy16(&Bs[ldsoff[i]], Bt + bgbase[i] + kb);
    }
    __syncthreads();   // drains vmcnt(0): LDS staged
    #pragma unroll
    for (int ks = 0; ks < 2; ks++) {
      bf16x8 af[4], bfr[4];
      #pragma unroll
      for (int t = 0; t < 4; t++) af[t]  = *(const bf16x8*)&As[aoff[t][ks]];
      #pragma unroll
      for (int t = 0; t < 4; t++) bfr[t] = *(const bf16x8*)&Bs[boff[t][ks]];
      #pragma unroll
      for (int mt = 0; mt < 4; mt++)
        #pragma unroll
        for (int nt = 0; nt < 4; nt++)
          acc[mt][nt] = __builtin_amdgcn_mfma_f32_16x16x32_bf16(af[mt], bfr[nt], acc[mt][nt], 0, 0, 0);
    }
    __syncthreads();   // protect LDS before next stage
  }

  // epilogue: D[row = q*4+v][col = ln] per 16x16 tile
  if (MODE == 0) {
    const float* bias = (g == 0) ? bias1 : ((g == 1) ? bias2 : bias3);
    int cbase = n0t - g * FEAT + wn * 64;
    #pragma unroll
    for (int nt = 0; nt < 4; nt++) {
      int c = cbase + nt * 16 + ln;
      float bv = bias[c];
      #pragma unroll
      for (int mt = 0; mt < 4; mt++) {
        int mrow = m0 + wm * 64 + mt * 16 + q * 4;
        #pragma unroll
        for (int v = 0; v < 4; v++) {
          int m = mrow + v;
          int l = m % SEQ;
          float val = acc[mt][nt][v] + bv;
          val = val > 0.f ? val : 0.f;
          if (l >= SEQ - g) val = 0.f;    // reference zero-padding for short convs
          P[((long)g * MC + m) * FEAT + c] = (bf16_t)val;
        }
      }
    }
  } else {
    #pragma unroll
    for (int nt = 0; nt < 4; nt++) {
      int c = n0t + wn * 64 + nt * 16 + ln;
      float bv = bias1[c];
      #pragma unroll
      for (int mt = 0; mt < 4; mt++) {
        int mrow = m0 + wm * 64 + mt * 16 + q * 4;
        #pragma unroll
        for (int v = 0; v < 4; v++)
          S[(long)(mrow + v) * FEAT + c] = acc[mt][nt][v] + bv;
      }
    }
  }
}

// ---------- epilogue: one block per batch element (chunk-local) ----------
__global__ __launch_bounds__(256)
void epilogue_k(const bf16_t* __restrict__ P, float* __restrict__ out, int b0) {
  const int bl = blockIdx.x;           // chunk-local batch index
  const long b = b0 + bl;              // global batch index
  const int t = threadIdx.x;
  const int lane = t & 63, w = t >> 6;
  const int c0 = t * 2;

  float code[SEQ][2];
  #pragma unroll
  for (int l = 0; l < SEQ; l++) { code[l][0] = 0.f; code[l][1] = 0.f; }
  float mg[3][2];

  #pragma unroll
  for (int gg = 0; gg < 3; gg++) {
    float mx0 = 0.f, mx1 = 0.f;
    #pragma unroll
    for (int l = 0; l < SEQ; l++) {
      uint32_t u = *(const uint32_t*)&P[((long)gg * MC + (long)bl * SEQ + l) * FEAT + c0];
      float v0 = __builtin_bit_cast(float, u << 16);
      float v1 = __builtin_bit_cast(float, u & 0xffff0000u);
      code[l][0] = fmaxf(code[l][0], v0);
      code[l][1] = fmaxf(code[l][1], v1);
      mx0 = fmaxf(mx0, v0); mx1 = fmaxf(mx1, v1);
    }
    mg[gg][0] = mx0; mg[gg][1] = mx1;
  }

  __shared__ float red[SEQ][4];
  __shared__ float redp[4];

  #pragma unroll
  for (int l = 0; l < SEQ; l++) {
    float s = code[l][0] * code[l][0] + code[l][1] * code[l][1];
    #pragma unroll
    for (int off = 32; off; off >>= 1) s += __shfl_xor(s, off, 64);
    if (lane == 0) red[l][w] = s;
  }
  float p0 = (mg[0][0] + mg[1][0] + mg[2][0]) * (1.f / 3.f);
  float p1 = (mg[0][1] + mg[1][1] + mg[2][1]) * (1.f / 3.f);
  float sp = p0 * p0 + p1 * p1;
  #pragma unroll
  for (int off = 32; off; off >>= 1) sp += __shfl_xor(sp, off, 64);
  if (lane == 0) redp[w] = sp;
  __syncthreads();

  float rnorm[SEQ];
  #pragma unroll
  for (int l = 0; l < SEQ; l++) {
    float s = red[l][0] + red[l][1] + red[l][2] + red[l][3];
    rnorm[l] = 1.f / fmaxf(sqrtf(s), 1e-12f);
  }
  float sP = redp[0] + redp[1] + redp[2] + redp[3];
  float rnp = 1.f / fmaxf(sqrtf(sP), 1e-12f);

  // words_out [b][c][l]
  #pragma unroll
  for (int cc = 0; cc < 2; cc++) {
    long base = b * (FEAT * SEQ) + (long)(c0 + cc) * SEQ;
    #pragma unroll
    for (int l0 = 0; l0 < SEQ; l0 += 4) {
      float4 v;
      v.x = code[l0 + 0][cc] * rnorm[l0 + 0];
      v.y = code[l0 + 1][cc] * rnorm[l0 + 1];
      v.z = code[l0 + 2][cc] * rnorm[l0 + 2];
      v.w = code[l0 + 3][cc] * rnorm[l0 + 3];
      *(float4*)&out[base + l0] = v;
    }
  }
  // word_vector [b][c]
  out[WV_BASE + b * FEAT + c0]     = p0 * rnp;
  out[WV_BASE + b * FEAT + c0 + 1] = p1 * rnp;
}

// ---------- launch ----------
extern "C" void kernel_launch(void* const* d_in, const int* in_sizes, int n_in,
                              void* d_out, int out_size, void* d_ws, size_t ws_size,
                              hipStream_t stream) {
  const float* words = (const float*)d_in[0];
  const float* sent  = (const float*)d_in[1];
  const float* W1 = (const float*)d_in[2];
  const float* b1 = (const float*)d_in[3];
  const float* W2 = (const float*)d_in[4];
  const float* b2 = (const float*)d_in[5];
  const float* W3 = (const float*)d_in[6];
  const float* b3 = (const float*)d_in[7];
  const float* Wp = (const float*)d_in[8];
  const float* bp = (const float*)d_in[9];
  float* out = (float*)d_out;
  char* ws = (char*)d_ws;

  if (ws_size < (size_t)WS_NEED) return;   // refuse to scribble OOB

  bf16_t* Bt    = (bf16_t*)(ws + BT_OFF);
  bf16_t* Wpt   = (bf16_t*)(ws + WPT_OFF);
  bf16_t* sentX = (bf16_t*)(ws + SENTX_OFF);
  bf16_t* Xpad  = (bf16_t*)(ws + XPAD_OFF);
  bf16_t* P     = (bf16_t*)(ws + P_OFF);

  // weights + sentence path (once)
  pack_bt<<<13824, 256, 0, stream>>>(W1, W2, W3, Bt);    // 1536*2304/256
  pack_wpt<<<1536, 256, 0, stream>>>(Wp, Wpt);           // 512*768/256
  pack_sent<<<3072, 256, 0, stream>>>(sent, sentX);      // 4096*768/4/256
  gemm_k<1><<<dim3(32, 4), 256, 0, stream>>>(sentX, Wpt, bp, bp, bp, nullptr, out + SENT_BASE);

  // conv path, chunked over batch to bound workspace
  for (int ch = 0; ch < NCHUNK; ch++) {
    int b0 = ch * CB;
    pack_xpad<<<16896, 256, 0, stream>>>(words + (long)b0 * SEQ * EMB, Xpad);  // CB*22*768/4/256
    gemm_k<0><<<dim3(160, 12), 256, 0, stream>>>(Xpad, Bt, b1, b2, b3, P, nullptr);
    epilogue_k<<<CB, 256, 0, stream>>>(P, out, b0);
  }
}